// Round 9
// baseline (124.076 us; speedup 1.0000x reference)
//
#include <hip/hip_runtime.h>

// ============================================================================
// MFMA formulation. Per filter f (random window at pos (si,sj), 0..59):
//   D[36 conv positions][1024 batches] = Wt[36][K=256] x Xwin[K=256][1024]
// K indexes window pixels, octet-aligned: k -> (wr = k/24, rem = k%24),
// padded pixel col pc = 8*(sj>>3) + rem, padded row = si + wr. 10 rows x 24
// cols (3 octets) covers the needed 10x10 slab for any sj&7; k >= 240 and
// out-of-support entries are zero in Wt (and read the zeroed octet 0).
//
// Xh layout: fp16 [700 octets (prow*10+ocol)][1024 batches][8 px] = 11.5 MB.
//   B-fragment: lane reads 16 B at Xh[oct(k)][bbase + lane&15][*] -> lanes
//   0..15 contiguous 256 B. Per-XCD batch slice (bg=blockIdx&3) = 2.9 MB < L2.
// Wf layout: fp16 fragment-ordered [f][s 8][mt 3][lane 64][e 8] = 24 KB/filter.
// MFMA 16x16x32 f16 layouts (per guide): A[m=lane&15][k=quad*8+e],
//   B[k=quad*8+e][n=lane&15], D[row=quad*4+reg][col=lane&15].
// ============================================================================

#define PAD_DIM   70
#define OCT_BYTES 16384          // 1024 batches * 8 px * 2 B per octet
#define XH_BYTES  ((size_t)700 * OCT_BYTES)          // 11,468,800
#define WF_FILTER 24576          // 1536 fragments * 16 B

typedef _Float16 v8h __attribute__((ext_vector_type(8)));
typedef float    v4f __attribute__((ext_vector_type(4)));

// ---------------- prep: Xh build + zero octets + Wf (Toeplitz, frag order) ----
__global__ __launch_bounds__(256) void prep_kernel(
    const float* __restrict__ X, const float* __restrict__ W,
    const int* __restrict__ pos,
    _Float16* __restrict__ Xh, _Float16* __restrict__ Wf)
{
    const int bid = blockIdx.x;
    const int t   = threadIdx.x;
    if (bid < 1024) {
        // interior: image row r, 64-batch group; stage [64 b][64 c] then emit octets
        __shared__ float T[64 * 65];
        const int r = bid >> 4, bgrp = bid & 15;
        #pragma unroll
        for (int i = 0; i < 16; ++i) {
            int flat = i * 256 + t;
            int b = flat >> 6, c = flat & 63;
            T[b * 65 + c] = X[(size_t)(bgrp * 64 + b) * 4096 + r * 64 + c];
        }
        __syncthreads();
        for (int idx = t; idx < 9 * 64; idx += 256) {
            int o = idx >> 6, b = idx & 63;     // octet col 0..8 (9 zeroed elsewhere)
            v8h v;
            #pragma unroll
            for (int e = 0; e < 8; ++e) {
                int c = 8 * o + e - 3;          // padded col -> image col
                v[e] = (c >= 0 && c < 64) ? (_Float16)T[b * 65 + c] : (_Float16)0.f;
            }
            *(v8h*)((char*)Xh + (size_t)((r + 3) * 10 + o) * OCT_BYTES
                              + (bgrp * 64 + b) * 16) = v;
        }
    } else if (bid < 1148) {
        // zero octets: prow {0,1,2,67,68,69} x ocol 0..9 (60) + ocol 9 x prow 3..66 (64)
        int zi = bid - 1024, oct;
        if (zi < 60) { int pr = zi / 10; pr = pr < 3 ? pr : pr + 64; oct = pr * 10 + zi % 10; }
        else         { oct = (3 + (zi - 60)) * 10 + 9; }
        uint4* q = (uint4*)((char*)Xh + (size_t)oct * OCT_BYTES);
        uint4 z = {0, 0, 0, 0};
        for (int i = t; i < 1024; i += 256) q[i] = z;
    } else {
        // Wf: Toeplitz-expanded weights in A-fragment order
        const int f = bid - 1148;
        __shared__ _Float16 wl[25];
        if (t < 25) wl[t] = (_Float16)W[f * 25 + t];
        const int sjoff = pos[2 * f + 1] & 7;
        __syncthreads();
        for (int flat = t; flat < 1536; flat += 256) {
            int s  = flat / 192;                // 192 = 3*64
            int r1 = flat - s * 192;
            int mt = r1 >> 6, ln = r1 & 63;
            int m    = mt * 16 + (ln & 15);     // conv position p
            int kb   = s * 32 + (ln >> 4) * 8;
            v8h v;
            if (m < 36 && kb < 240) {
                int y  = (m * 43) >> 8;         // m/6 for m<48
                int x  = m - 6 * y;
                int wr = (kb * 171) >> 12;      // kb/24 for kb<256, kb%8==0
                int r_ = wr - y;
                int rem0 = kb - wr * 24;
                #pragma unroll
                for (int e = 0; e < 8; ++e) {
                    int c_ = (rem0 + e - sjoff) - x;       // wc - x
                    bool ok = (r_ >= 0 && r_ < 5 && c_ >= 0 && c_ < 5);
                    int wi = ok ? (r_ * 5 + c_) : 0;
                    _Float16 wv = wl[wi];
                    v[e] = ok ? wv : (_Float16)0.f;
                }
            } else {
                #pragma unroll
                for (int e = 0; e < 8; ++e) v[e] = (_Float16)0.f;
            }
            *(v8h*)((char*)Wf + (size_t)f * WF_FILTER + flat * 16) = v;
        }
    }
}

// ---------------- main: block = (filter, 256-batch group), 4 waves x 4 ntiles ----
__global__ __launch_bounds__(256, 4) void filters_main(
    const _Float16* __restrict__ Xh, const _Float16* __restrict__ Wf,
    const float* __restrict__ bias, const int* __restrict__ pos,
    float* __restrict__ out)
{
    __shared__ float PL[4][16 * 48];   // per-wave [col 16][pos 48] dump
    __shared__ float PQ[4][64];        // per-wave [col 16][quadrant 4]

    const int t    = threadIdx.x;
    const int lane = t & 63;
    const int wv   = t >> 6;
    const int bg   = blockIdx.x & 3;          // batch group -> XCD x serves bg = x&3
    const int f    = blockIdx.x >> 2;

    const int si = pos[2 * f], sj = pos[2 * f + 1];
    const int o0 = sj >> 3;
    const int n16 = lane & 15, quad = lane >> 4;

    v4f acc[3][4];
    #pragma unroll
    for (int mt = 0; mt < 3; ++mt)
        #pragma unroll
        for (int i = 0; i < 4; ++i) acc[mt][i] = (v4f)0.0f;

    const char* xb = (const char*)Xh + (size_t)(bg * 256 + wv * 64 + n16) * 16;
    const char* wb = (const char*)Wf + (size_t)f * WF_FILTER + lane * 16;

    #pragma unroll
    for (int s = 0; s < 8; ++s) {
        int kb  = s * 32 + quad * 8;
        int wr  = (kb * 171) >> 12;
        int sub = (kb - wr * 24) >> 3;
        int oct = (si + wr) * 10 + o0 + sub;
        oct = (kb < 240) ? oct : 0;           // K-pad tail -> zeroed octet 0
        const char* bp = xb + (size_t)oct * OCT_BYTES;
        v8h B0 = *(const v8h*)(bp);
        v8h B1 = *(const v8h*)(bp + 256);
        v8h B2 = *(const v8h*)(bp + 512);
        v8h B3 = *(const v8h*)(bp + 768);
        const char* ap = wb + s * 3072;       // [s][mt] strides 3072/1024
        v8h A0 = *(const v8h*)(ap);
        v8h A1 = *(const v8h*)(ap + 1024);
        v8h A2 = *(const v8h*)(ap + 2048);
        acc[0][0] = __builtin_amdgcn_mfma_f32_16x16x32_f16(A0, B0, acc[0][0], 0, 0, 0);
        acc[0][1] = __builtin_amdgcn_mfma_f32_16x16x32_f16(A0, B1, acc[0][1], 0, 0, 0);
        acc[0][2] = __builtin_amdgcn_mfma_f32_16x16x32_f16(A0, B2, acc[0][2], 0, 0, 0);
        acc[0][3] = __builtin_amdgcn_mfma_f32_16x16x32_f16(A0, B3, acc[0][3], 0, 0, 0);
        acc[1][0] = __builtin_amdgcn_mfma_f32_16x16x32_f16(A1, B0, acc[1][0], 0, 0, 0);
        acc[1][1] = __builtin_amdgcn_mfma_f32_16x16x32_f16(A1, B1, acc[1][1], 0, 0, 0);
        acc[1][2] = __builtin_amdgcn_mfma_f32_16x16x32_f16(A1, B2, acc[1][2], 0, 0, 0);
        acc[1][3] = __builtin_amdgcn_mfma_f32_16x16x32_f16(A1, B3, acc[1][3], 0, 0, 0);
        acc[2][0] = __builtin_amdgcn_mfma_f32_16x16x32_f16(A2, B0, acc[2][0], 0, 0, 0);
        acc[2][1] = __builtin_amdgcn_mfma_f32_16x16x32_f16(A2, B1, acc[2][1], 0, 0, 0);
        acc[2][2] = __builtin_amdgcn_mfma_f32_16x16x32_f16(A2, B2, acc[2][2], 0, 0, 0);
        acc[2][3] = __builtin_amdgcn_mfma_f32_16x16x32_f16(A2, B3, acc[2][3], 0, 0, 0);
    }

    // epilogue: per ntile, dump D to LDS (col-major), 3x3/stride-3 pool, store
    float* pl = PL[wv];
    float* pq = PQ[wv];
    const float bv = bias[f];
    const int py = quad >> 1, px = quad & 1;  // this lane's pool quadrant task
    #pragma unroll
    for (int i = 0; i < 4; ++i) {
        #pragma unroll
        for (int mt = 0; mt < 3; ++mt)
            *(v4f*)&pl[n16 * 48 + mt * 16 + quad * 4] = acc[mt][i];
        // wave-internal LDS dependency; compiler inserts lgkmcnt waits
        float mx = pl[n16 * 48 + (3 * py) * 6 + 3 * px];
        #pragma unroll
        for (int y = 0; y < 3; ++y)
            #pragma unroll
            for (int x = 0; x < 3; ++x)
                mx = fmaxf(mx, pl[n16 * 48 + (3 * py + y) * 6 + (3 * px + x)]);
        pq[n16 * 4 + quad] = mx + bv;
        if (lane < 16) {
            v4f o = *(v4f*)&pq[lane * 4];
            int b = bg * 256 + (wv * 4 + i) * 16 + lane;
            *(v4f*)&out[(size_t)b * 4096 + f * 4] = o;
        }
    }
}

extern "C" void kernel_launch(void* const* d_in, const int* in_sizes, int n_in,
                              void* d_out, int out_size, void* d_ws, size_t ws_size,
                              hipStream_t stream) {
    const float* X    = (const float*)d_in[0];
    const float* W    = (const float*)d_in[1];
    const float* bias = (const float*)d_in[2];
    const int*   pos  = (const int*)d_in[3];
    float* out = (float*)d_out;
    _Float16* Xh = (_Float16*)d_ws;                       // 11.5 MB
    _Float16* Wf = (_Float16*)((char*)d_ws + XH_BYTES);   // 25.2 MB

    prep_kernel<<<2172, 256, 0, stream>>>(X, W, pos, Xh, Wf);
    filters_main<<<4096, 256, 0, stream>>>(Xh, Wf, bias, pos, out);
}

// Round 10
// 119.453 us; speedup vs baseline: 1.0387x; 1.0387x over previous
//
#include <hip/hip_runtime.h>

// ============================================================================
// MFMA formulation. Per filter f (random window at pos (si,sj), 0..59):
//   D[48 rows][1024 batches] = Wt[48][K=256] x Xwin[K=256][1024]
// K indexes window pixels, octet-aligned: k -> (wr = k/24, rem = k%24),
// padded pixel col pc = 8*(sj>>3) + rem, padded row = si + wr. 10 rows x 24
// cols (3 octets) covers the needed 10x10 slab for any sj&7; k >= 240 -> 0.
//
// m-PERMUTATION (R10): D rows are quadrant-banded: pool quadrant q owns rows
// 12q..12q+11 = its 9 conv positions + 3 duplicates (max unaffected). 4-row
// (mt,quad) reg groups never straddle a 12-boundary, so each lane's 4 regs of
// a given mt belong to ONE quadrant: qd(mt,quad) = (4*mt+quad)/3. Epilogue is
// register maxes + shfl_xor butterfly -- NO LDS (R9 had 1.3e7 bank conflicts).
//
// Xh layout: fp16 [700 octets (prow*10+ocol)][1024 batches][8 px] = 11.5 MB.
//   B-fragment: lanes 0..15 contiguous 256 B. Per-XCD batch slice (bg) 2.9 MB.
// Wf layout: fp16 fragment-ordered [f][s 8][mt 3][lane 64][e 8] = 24 KB/filter.
// MFMA 16x16x32 f16 layouts: A[m=lane&15][k=quad*8+e], B[k=quad*8+e][n=lane&15],
//   D[row=quad*4+reg][col=lane&15].
// ============================================================================

#define PAD_DIM   70
#define OCT_BYTES 16384          // 1024 batches * 8 px * 2 B per octet
#define XH_BYTES  ((size_t)700 * OCT_BYTES)          // 11,468,800
#define WF_FILTER 24576          // 1536 fragments * 16 B

typedef _Float16 v8h __attribute__((ext_vector_type(8)));
typedef float    v4f __attribute__((ext_vector_type(4)));

// ---------------- prep: Xh build + zero octets + Wf (Toeplitz, frag order) ----
__global__ __launch_bounds__(256) void prep_kernel(
    const float* __restrict__ X, const float* __restrict__ W,
    const int* __restrict__ pos,
    _Float16* __restrict__ Xh, _Float16* __restrict__ Wf)
{
    const int bid = blockIdx.x;
    const int t   = threadIdx.x;
    if (bid < 1024) {
        // interior: image row r, 64-batch group; stage [64 b][64 c] then emit octets
        __shared__ float T[64 * 65];
        const int r = bid >> 4, bgrp = bid & 15;
        #pragma unroll
        for (int i = 0; i < 16; ++i) {
            int flat = i * 256 + t;
            int b = flat >> 6, c = flat & 63;
            T[b * 65 + c] = X[(size_t)(bgrp * 64 + b) * 4096 + r * 64 + c];
        }
        __syncthreads();
        for (int idx = t; idx < 9 * 64; idx += 256) {
            int o = idx >> 6, b = idx & 63;     // octet col 0..8 (9 zeroed elsewhere)
            v8h v;
            #pragma unroll
            for (int e = 0; e < 8; ++e) {
                int c = 8 * o + e - 3;          // padded col -> image col
                v[e] = (c >= 0 && c < 64) ? (_Float16)T[b * 65 + c] : (_Float16)0.f;
            }
            *(v8h*)((char*)Xh + (size_t)((r + 3) * 10 + o) * OCT_BYTES
                              + (bgrp * 64 + b) * 16) = v;
        }
    } else if (bid < 1148) {
        // zero octets: prow {0,1,2,67,68,69} x ocol 0..9 (60) + ocol 9 x prow 3..66 (64)
        int zi = bid - 1024, oct;
        if (zi < 60) { int pr = zi / 10; pr = pr < 3 ? pr : pr + 64; oct = pr * 10 + zi % 10; }
        else         { oct = (3 + (zi - 60)) * 10 + 9; }
        uint4* q = (uint4*)((char*)Xh + (size_t)oct * OCT_BYTES);
        uint4 z = {0, 0, 0, 0};
        for (int i = t; i < 1024; i += 256) q[i] = z;
    } else {
        // Wf: Toeplitz-expanded weights in A-fragment order, quadrant-banded rows
        const int f = bid - 1148;
        __shared__ _Float16 wl[25];
        if (t < 25) wl[t] = (_Float16)W[f * 25 + t];
        const int sjoff = pos[2 * f + 1] & 7;
        __syncthreads();
        for (int flat = t; flat < 1536; flat += 256) {
            int s  = flat / 192;                // 192 = 3*64
            int r1 = flat - s * 192;
            int mt = r1 >> 6, ln = r1 & 63;
            int m    = mt * 16 + (ln & 15);     // D/A row index 0..47
            int kb   = s * 32 + (ln >> 4) * 8;
            v8h v;
            if (kb < 240) {
                // row m -> conv position via quadrant-banded mapping
                int q   = m / 12;               // pool quadrant 0..3
                int rem = m - 12 * q;
                int j   = (rem < 9) ? rem : (rem - 9);   // duplicate rows 9..11
                int jy  = j / 3;
                int y   = 3 * (q >> 1) + jy;
                int x   = 3 * (q & 1) + (j - 3 * jy);
                int wr  = (kb * 171) >> 12;     // kb/24
                int r_  = wr - y;
                int rem0 = kb - wr * 24;
                #pragma unroll
                for (int e = 0; e < 8; ++e) {
                    int c_ = (rem0 + e - sjoff) - x;       // wc - x
                    bool ok = (r_ >= 0 && r_ < 5 && c_ >= 0 && c_ < 5);
                    int wi = ok ? (r_ * 5 + c_) : 0;
                    _Float16 wv = wl[wi];
                    v[e] = ok ? wv : (_Float16)0.f;
                }
            } else {
                #pragma unroll
                for (int e = 0; e < 8; ++e) v[e] = (_Float16)0.f;
            }
            *(v8h*)((char*)Wf + (size_t)f * WF_FILTER + flat * 16) = v;
        }
    }
}

// ---------------- main: block = (filter, 256-batch group), 4 waves x 4 ntiles ----
__global__ __launch_bounds__(256, 4) void filters_main(
    const _Float16* __restrict__ Xh, const _Float16* __restrict__ Wf,
    const float* __restrict__ bias, const int* __restrict__ pos,
    float* __restrict__ out)
{
    const int t    = threadIdx.x;
    const int lane = t & 63;
    const int wv   = t >> 6;
    const int bg   = blockIdx.x & 3;          // batch group -> XCD pin
    const int f    = blockIdx.x >> 2;

    const int si = pos[2 * f], sj = pos[2 * f + 1];
    const int o0 = sj >> 3;
    const int n16 = lane & 15, quad = lane >> 4;

    v4f acc[3][4];
    #pragma unroll
    for (int mt = 0; mt < 3; ++mt)
        #pragma unroll
        for (int i = 0; i < 4; ++i) acc[mt][i] = (v4f)0.0f;

    const char* xb = (const char*)Xh + (size_t)(bg * 256 + wv * 64 + n16) * 16;
    const char* wb = (const char*)Wf + (size_t)f * WF_FILTER + lane * 16;

    #pragma unroll
    for (int s = 0; s < 8; ++s) {
        int kb  = s * 32 + quad * 8;
        int wr  = (kb * 171) >> 12;
        int sub = (kb - wr * 24) >> 3;
        int oct = (si + wr) * 10 + o0 + sub;
        oct = (kb < 240) ? oct : 0;           // K-pad tail -> zeroed octet 0
        const char* bp = xb + (size_t)oct * OCT_BYTES;
        v8h B0 = *(const v8h*)(bp);
        v8h B1 = *(const v8h*)(bp + 256);
        v8h B2 = *(const v8h*)(bp + 512);
        v8h B3 = *(const v8h*)(bp + 768);
        const char* ap = wb + s * 3072;       // [s][mt] strides 3072/1024
        v8h A0 = *(const v8h*)(ap);
        v8h A1 = *(const v8h*)(ap + 1024);
        v8h A2 = *(const v8h*)(ap + 2048);
        acc[0][0] = __builtin_amdgcn_mfma_f32_16x16x32_f16(A0, B0, acc[0][0], 0, 0, 0);
        acc[0][1] = __builtin_amdgcn_mfma_f32_16x16x32_f16(A0, B1, acc[0][1], 0, 0, 0);
        acc[0][2] = __builtin_amdgcn_mfma_f32_16x16x32_f16(A0, B2, acc[0][2], 0, 0, 0);
        acc[0][3] = __builtin_amdgcn_mfma_f32_16x16x32_f16(A0, B3, acc[0][3], 0, 0, 0);
        acc[1][0] = __builtin_amdgcn_mfma_f32_16x16x32_f16(A1, B0, acc[1][0], 0, 0, 0);
        acc[1][1] = __builtin_amdgcn_mfma_f32_16x16x32_f16(A1, B1, acc[1][1], 0, 0, 0);
        acc[1][2] = __builtin_amdgcn_mfma_f32_16x16x32_f16(A1, B2, acc[1][2], 0, 0, 0);
        acc[1][3] = __builtin_amdgcn_mfma_f32_16x16x32_f16(A1, B3, acc[1][3], 0, 0, 0);
        acc[2][0] = __builtin_amdgcn_mfma_f32_16x16x32_f16(A2, B0, acc[2][0], 0, 0, 0);
        acc[2][1] = __builtin_amdgcn_mfma_f32_16x16x32_f16(A2, B1, acc[2][1], 0, 0, 0);
        acc[2][2] = __builtin_amdgcn_mfma_f32_16x16x32_f16(A2, B2, acc[2][2], 0, 0, 0);
        acc[2][3] = __builtin_amdgcn_mfma_f32_16x16x32_f16(A2, B3, acc[2][3], 0, 0, 0);
    }

    // ---- epilogue: in-register quadrant maxes + shfl butterfly, no LDS ----
    // qd(mt) for this lane's quad: which pool quadrant its 4 regs belong to
    const int qd0 = quad / 3;            // (0*4+quad)/3: 0,0,0,1
    const int qd1 = (4 + quad) / 3;      // 1,1,2,2
    const int qd2 = (8 + quad) / 3;      // 2,3,3,3
    float sel[3][4];
    #pragma unroll
    for (int j = 0; j < 4; ++j) {
        sel[0][j] = (qd0 == j) ? 0.0f : -INFINITY;
        sel[1][j] = (qd1 == j) ? 0.0f : -INFINITY;
        sel[2][j] = (qd2 == j) ? 0.0f : -INFINITY;
    }
    const float bv = bias[f];

    #pragma unroll
    for (int i = 0; i < 4; ++i) {
        float r4[3];
        #pragma unroll
        for (int mt = 0; mt < 3; ++mt)
            r4[mt] = fmaxf(fmaxf(acc[mt][i][0], acc[mt][i][1]),
                           fmaxf(acc[mt][i][2], acc[mt][i][3]));
        float pm[4];
        #pragma unroll
        for (int j = 0; j < 4; ++j)
            pm[j] = fmaxf(fmaxf(r4[0] + sel[0][j], r4[1] + sel[1][j]),
                          r4[2] + sel[2][j]);
        #pragma unroll
        for (int j = 0; j < 4; ++j) {
            pm[j] = fmaxf(pm[j], __shfl_xor(pm[j], 16, 64));
            pm[j] = fmaxf(pm[j], __shfl_xor(pm[j], 32, 64));
        }
        if (lane < 16) {
            v4f o;
            o[0] = pm[0] + bv; o[1] = pm[1] + bv;
            o[2] = pm[2] + bv; o[3] = pm[3] + bv;
            int b = bg * 256 + (wv * 4 + i) * 16 + lane;
            *(v4f*)&out[(size_t)b * 4096 + f * 4] = o;
        }
    }
}

extern "C" void kernel_launch(void* const* d_in, const int* in_sizes, int n_in,
                              void* d_out, int out_size, void* d_ws, size_t ws_size,
                              hipStream_t stream) {
    const float* X    = (const float*)d_in[0];
    const float* W    = (const float*)d_in[1];
    const float* bias = (const float*)d_in[2];
    const int*   pos  = (const int*)d_in[3];
    float* out = (float*)d_out;
    _Float16* Xh = (_Float16*)d_ws;                       // 11.5 MB
    _Float16* Wf = (_Float16*)((char*)d_ws + XH_BYTES);   // 25.2 MB

    prep_kernel<<<2172, 256, 0, stream>>>(X, W, pos, Xh, Wf);
    filters_main<<<4096, 256, 0, stream>>>(Xh, Wf, bias, pos, out);
}